// Round 2
// baseline (512.398 us; speedup 1.0000x reference)
//
#include <hip/hip_runtime.h>
#include <cmath>

typedef __bf16 bf16x8 __attribute__((ext_vector_type(8)));
typedef float f32x4 __attribute__((ext_vector_type(4)));
typedef unsigned short us8 __attribute__((ext_vector_type(8)));

__device__ __forceinline__ unsigned short f2bf(float f) {
    union { float f; unsigned u; } x; x.f = f;
    unsigned u = x.u + 0x7FFFu + ((x.u >> 16) & 1u);
    return (unsigned short)(u >> 16);
}
__device__ __forceinline__ float bf2f(unsigned short h) {
    union { unsigned u; float f; } x; x.u = ((unsigned)h) << 16;
    return x.f;
}

// pack two f32x4 into bf16x8 (RNE via hw cvt)
__device__ __forceinline__ us8 pack8(f32x4 a, f32x4 b) {
    union { bf16x8 h; us8 u; } cv;
    cv.h[0] = (__bf16)a[0]; cv.h[1] = (__bf16)a[1];
    cv.h[2] = (__bf16)a[2]; cv.h[3] = (__bf16)a[3];
    cv.h[4] = (__bf16)b[0]; cv.h[5] = (__bf16)b[1];
    cv.h[6] = (__bf16)b[2]; cv.h[7] = (__bf16)b[3];
    return cv.u;
}

// load 8 consecutive fp32, convert to bf16x8 (as us8)
__device__ __forceinline__ us8 cvt8(const float* p) {
    f32x4 a = *(const f32x4*)p;
    f32x4 b = *(const f32x4*)(p + 4);
    return pack8(a, b);
}

__device__ __forceinline__ void gl2lds16(const unsigned short* g, unsigned short* l) {
    __builtin_amdgcn_global_load_lds(
        (const __attribute__((address_space(1))) unsigned int*)g,
        (__attribute__((address_space(3))) unsigned int*)l, 16, 0, 0);
}

// 4 weight matrices (1M floats each) in one launch; blockIdx.y selects matrix
__global__ __launch_bounds__(256)
void cvt_w4(const float* __restrict__ s0, const float* __restrict__ s1,
            const float* __restrict__ s2, const float* __restrict__ s3,
            unsigned short* __restrict__ d0, unsigned short* __restrict__ d1,
            unsigned short* __restrict__ d2, unsigned short* __restrict__ d3) {
    const float* sp[4] = {s0, s1, s2, s3};
    unsigned short* dp[4] = {d0, d1, d2, d3};
    const float* src = sp[blockIdx.y];
    unsigned short* dst = dp[blockIdx.y];
    const size_t i = ((size_t)blockIdx.x * 256 + threadIdx.x) * 8;
    *(us8*)(dst + i) = cvt8(src + i);
}

// XCD-chunked swizzle: dispatch slot s -> work w so slots with equal s%8
// (same XCD) process contiguous w. nwg=1024, 1024%8==0 -> bijective.
// Each XCD then owns 16 contiguous m-tiles x all 8 n-tiles.
__device__ __forceinline__ void swz_tiles(int& m0, int& n0) {
    const int slot = blockIdx.x + (blockIdx.y << 3);
    const int w = ((slot & 7) << 7) | (slot >> 3);
    m0 = (w >> 3) << 7;
    n0 = (w & 7) << 7;
}

// ---------------------------------------------------------------------------
// Projection GEMM: Y[m,n] = sum_k A[m,k]*W[n,k] + bias[n]; M=16384,N=1024,K=1024
// A is fp32; conversion fused into staging (T14: load-early fp32 -> MFMA ->
// cvt + ds_write-late). W: gl2lds of pre-converted bf16 (WBF) or fp32 cvt.
// 2-phase double-buffered, one barrier per K-iter.
// MODE 1: v = exp(clamp(y)); transposed bf16 outT [B][1024][4096]; col sums->S
// MODE 2: v = y;             transposed bf16 outT
// ---------------------------------------------------------------------------
template<int MODE, bool WBF>
__global__ __launch_bounds__(256)
void gemm_proj(const float* __restrict__ A, const void* __restrict__ Wp,
               const float* __restrict__ bias,
               unsigned short* __restrict__ outT,
               float* __restrict__ S)
{
    __shared__ __align__(16) unsigned short lds[17408];

    const int tid = threadIdx.x;
    const int wid = tid >> 6, lane = tid & 63;
    const int quad = lane >> 4, l16 = lane & 15;
    const int waveM = wid >> 1, waveN = wid & 1;
    int m0, n0; swz_tiles(m0, n0);
    const int srow = tid >> 2, scol = (tid & 3) * 8;
    const int r4 = lane >> 2, c8 = (lane & 3) * 8;

    f32x4 acc[4][4] = {};

    // prologue: tile 0 -> buf 0
    if (WBF) {
        const unsigned short* W = (const unsigned short*)Wp;
        for (int s = wid; s < 8; s += 4)
            gl2lds16(W + (size_t)(n0 + s * 16 + r4) * 1024 + c8, lds + 4096 + s * 512);
    } else {
        const float* W = (const float*)Wp;
#pragma unroll
        for (int p = 0; p < 2; ++p)
            *(us8*)(lds + 4096 + (p * 64 + srow) * 32 + scol) =
                cvt8(W + (size_t)(n0 + p * 64 + srow) * 1024 + scol);
    }
#pragma unroll
    for (int p = 0; p < 2; ++p)
        *(us8*)(lds + (p * 64 + srow) * 32 + scol) =
            cvt8(A + (size_t)(m0 + p * 64 + srow) * 1024 + scol);
    __syncthreads();

    int cur = 0;
    for (int k0 = 0; k0 < 1024; k0 += 32) {
        const int nxt = cur ^ 1;
        const bool pf = (k0 < 992);
        f32x4 pa[2][2], pw[2][2];
        if (pf) {
            // load-early: issue fp32 A(t+1) global loads; latency hides under MFMA
#pragma unroll
            for (int p = 0; p < 2; ++p) {
                const float* src = A + (size_t)(m0 + p * 64 + srow) * 1024 + k0 + 32 + scol;
                pa[p][0] = *(const f32x4*)src;
                pa[p][1] = *(const f32x4*)(src + 4);
            }
            if (WBF) {
                const unsigned short* W = (const unsigned short*)Wp;
                for (int s = wid; s < 8; s += 4)
                    gl2lds16(W + (size_t)(n0 + s * 16 + r4) * 1024 + k0 + 32 + c8,
                             lds + nxt * 8192 + 4096 + s * 512);
            } else {
                const float* W = (const float*)Wp;
#pragma unroll
                for (int p = 0; p < 2; ++p) {
                    const float* srcw = W + (size_t)(n0 + p * 64 + srow) * 1024 + k0 + 32 + scol;
                    pw[p][0] = *(const f32x4*)srcw;
                    pw[p][1] = *(const f32x4*)(srcw + 4);
                }
            }
        }
        const unsigned short* ldsA = lds + cur * 8192;
        const unsigned short* ldsB = ldsA + 4096;
        bf16x8 af[4], bfr[4];
#pragma unroll
        for (int i = 0; i < 4; ++i)
            af[i] = *(const bf16x8*)(ldsA + (waveM * 64 + i * 16 + l16) * 32 + quad * 8);
#pragma unroll
        for (int j = 0; j < 4; ++j)
            bfr[j] = *(const bf16x8*)(ldsB + (waveN * 64 + j * 16 + l16) * 32 + quad * 8);
#pragma unroll
        for (int i = 0; i < 4; ++i)
#pragma unroll
            for (int j = 0; j < 4; ++j)
                acc[i][j] = __builtin_amdgcn_mfma_f32_16x16x32_bf16(af[i], bfr[j], acc[i][j], 0, 0, 0);
        if (pf) {
            // write-late into the idle buffer (nobody reads it until the barrier)
#pragma unroll
            for (int p = 0; p < 2; ++p)
                *(us8*)(lds + nxt * 8192 + (p * 64 + srow) * 32 + scol) = pack8(pa[p][0], pa[p][1]);
            if (!WBF) {
#pragma unroll
                for (int p = 0; p < 2; ++p)
                    *(us8*)(lds + nxt * 8192 + 4096 + (p * 64 + srow) * 32 + scol) = pack8(pw[p][0], pw[p][1]);
            }
        }
        __syncthreads();
        cur = nxt;
    }

    const int b = m0 >> 12, l0 = m0 & 4095;
#pragma unroll
    for (int j = 0; j < 4; ++j) {
        const int nn = waveN * 64 + j * 16 + l16;
        const float bc = bias[n0 + nn];
        float ssum = 0.f;
#pragma unroll
        for (int i = 0; i < 4; ++i)
#pragma unroll
            for (int r = 0; r < 4; ++r) {
                const int mm = waveM * 64 + i * 16 + quad * 4 + r;
                float v = acc[i][j][r] + bc;
                if (MODE == 1) v = expf(fminf(fmaxf(v, -30.f), 30.f)); // NaN/inf firewall
                lds[nn * 136 + mm] = f2bf(v);
                ssum += v;
            }
        if (MODE == 1) {
            ssum += __shfl_xor(ssum, 16);
            ssum += __shfl_xor(ssum, 32);
            if (lane < 16)
                atomicAdd(&S[(size_t)b * 1024 + n0 + waveN * 64 + j * 16 + lane], ssum);
        }
    }
    __syncthreads();
    const int seg = (tid & 15) * 8;
#pragma unroll
    for (int it = 0; it < 8; ++it) {
        const int nn = (tid >> 4) + it * 16;
        us8 v = *(const us8*)&lds[nn * 136 + seg];
        *(us8*)(outT + ((size_t)b * 1024 + n0 + nn) * 4096 + l0 + seg) = v;
    }
}

// ---------------------------------------------------------------------------
// Context: ctxf[b][h][e][d] += sum_l Vt[b][h*64+e][l] * Et[b][h*64+d][l]
// reg-prefetch double-buffer; grid (8,16,4) -> 512 blocks, 16 K-iters
// ---------------------------------------------------------------------------
__global__ __launch_bounds__(256)
void ctx_kernel(const unsigned short* __restrict__ Vt,
                const unsigned short* __restrict__ Et,
                float* __restrict__ ctxf)
{
    __shared__ __align__(16) unsigned short lds[8192];

    const int tid = threadIdx.x;
    const int wid = tid >> 6, lane = tid & 63;
    const int quad = lane >> 4, l16 = lane & 15;
    const int b = blockIdx.z, h = blockIdx.y;
    const int lbase = blockIdx.x * 512;

    const unsigned short* Arow = Vt + ((size_t)b * 1024 + h * 64) * 4096; // rows e
    const unsigned short* Brow = Et + ((size_t)b * 1024 + h * 64) * 4096; // rows d

    const int srow = tid >> 2;
    const int scol = (tid & 3) * 8;

    f32x4 acc[4] = {};

    {
        us8 va = *(const us8*)(Arow + (size_t)srow * 4096 + lbase + scol);
        us8 vb = *(const us8*)(Brow + (size_t)srow * 4096 + lbase + scol);
        *(us8*)(lds + srow * 32 + scol) = va;
        *(us8*)(lds + 2048 + srow * 32 + scol) = vb;
    }
    __syncthreads();

    int cur = 0;
    for (int k0 = 0; k0 < 512; k0 += 32) {
        const int nxt = cur ^ 1;
        us8 na = {}, nb = {};
        const bool pf = (k0 < 480);
        if (pf) {
            na = *(const us8*)(Arow + (size_t)srow * 4096 + lbase + k0 + 32 + scol);
            nb = *(const us8*)(Brow + (size_t)srow * 4096 + lbase + k0 + 32 + scol);
        }
        const unsigned short* ldsA = lds + cur * 4096;
        const unsigned short* ldsB = ldsA + 2048;
        bf16x8 a = *(const bf16x8*)(ldsA + (wid * 16 + l16) * 32 + quad * 8);
#pragma unroll
        for (int j = 0; j < 4; ++j) {
            bf16x8 bb = *(const bf16x8*)(ldsB + (j * 16 + l16) * 32 + quad * 8);
            acc[j] = __builtin_amdgcn_mfma_f32_16x16x32_bf16(a, bb, acc[j], 0, 0, 0);
        }
        if (pf) {
            *(us8*)(lds + nxt * 4096 + srow * 32 + scol) = na;
            *(us8*)(lds + nxt * 4096 + 2048 + srow * 32 + scol) = nb;
        }
        __syncthreads();
        cur = nxt;
    }
    float* base = ctxf + ((size_t)(b * 16 + h)) * 4096;
#pragma unroll
    for (int j = 0; j < 4; ++j)
#pragma unroll
        for (int r = 0; r < 4; ++r) {
            const int e = wid * 16 + quad * 4 + r;
            const int d = j * 16 + l16;
            atomicAdd(base + e * 64 + d, acc[j][r]);
        }
}

// ---------------------------------------------------------------------------
// Fused Q-projection + attention (two heads per 128-col tile).
// ctx normalization (ctxf/S -> bf16) fused into the ctx staging phase.
// staging buffers [0,16384) shorts; ldsQ [0,17408) post-loop; ldsC at 17408
// ---------------------------------------------------------------------------
template<bool WBF>
__global__ __launch_bounds__(256)
void gemm_qattn(const float* __restrict__ A, const void* __restrict__ Wp,
                const float* __restrict__ bias,
                const float* __restrict__ ctxf,
                const float* __restrict__ Sv,
                const unsigned short* __restrict__ Vt,
                const int* __restrict__ ec,
                unsigned short* __restrict__ att)
{
    __shared__ __align__(16) unsigned short lds[26624];
    unsigned short* ldsQ = lds;              // [128][136] after main loop
    unsigned short* ldsC = lds + 17408;      // [128][72] ctx rows (never aliased)

    const int tid = threadIdx.x;
    const int wid = tid >> 6, lane = tid & 63;
    const int quad = lane >> 4, l16 = lane & 15;
    const int waveM = wid >> 1, waveN = wid & 1;
    int m0, n0; swz_tiles(m0, n0);
    const int b = m0 >> 12;
    const int srow = tid >> 2, scol = (tid & 3) * 8;
    const int r4 = lane >> 2, c8 = (lane & 3) * 8;

    { // stage normalized ctx for both heads of this tile (fused ctx_norm)
        const int e2 = tid >> 1;
        const int sg = (tid & 1) * 32;
        const int hh = (n0 >> 6) + (e2 >> 6);
        const float* srcf = ctxf + (((size_t)(b * 16) + hh) * 64 + (e2 & 63)) * 64 + sg;
        const float* Sp = Sv + (size_t)b * 1024 + hh * 64 + sg;
#pragma unroll
        for (int u = 0; u < 4; ++u) {
            f32x4 c0 = *(const f32x4*)(srcf + u * 8);
            f32x4 c1 = *(const f32x4*)(srcf + u * 8 + 4);
            union { bf16x8 h; us8 uu; } cv;
#pragma unroll
            for (int j = 0; j < 4; ++j) cv.h[j] = (__bf16)(c0[j] / Sp[u * 8 + j]);
#pragma unroll
            for (int j = 0; j < 4; ++j) cv.h[4 + j] = (__bf16)(c1[j] / Sp[u * 8 + 4 + j]);
            *(us8*)&ldsC[e2 * 72 + sg + u * 8] = cv.uu;
        }
    }

    f32x4 acc[4][4] = {};

    // prologue: tile 0 -> buf 0
    if (WBF) {
        const unsigned short* W = (const unsigned short*)Wp;
        for (int s = wid; s < 8; s += 4)
            gl2lds16(W + (size_t)(n0 + s * 16 + r4) * 1024 + c8, lds + 4096 + s * 512);
    } else {
        const float* W = (const float*)Wp;
#pragma unroll
        for (int p = 0; p < 2; ++p)
            *(us8*)(lds + 4096 + (p * 64 + srow) * 32 + scol) =
                cvt8(W + (size_t)(n0 + p * 64 + srow) * 1024 + scol);
    }
#pragma unroll
    for (int p = 0; p < 2; ++p)
        *(us8*)(lds + (p * 64 + srow) * 32 + scol) =
            cvt8(A + (size_t)(m0 + p * 64 + srow) * 1024 + scol);
    __syncthreads();

    int cur = 0;
    for (int k0 = 0; k0 < 1024; k0 += 32) {
        const int nxt = cur ^ 1;
        const bool pf = (k0 < 992);
        f32x4 pa[2][2], pw[2][2];
        if (pf) {
#pragma unroll
            for (int p = 0; p < 2; ++p) {
                const float* src = A + (size_t)(m0 + p * 64 + srow) * 1024 + k0 + 32 + scol;
                pa[p][0] = *(const f32x4*)src;
                pa[p][1] = *(const f32x4*)(src + 4);
            }
            if (WBF) {
                const unsigned short* W = (const unsigned short*)Wp;
                for (int s = wid; s < 8; s += 4)
                    gl2lds16(W + (size_t)(n0 + s * 16 + r4) * 1024 + k0 + 32 + c8,
                             lds + nxt * 8192 + 4096 + s * 512);
            } else {
                const float* W = (const float*)Wp;
#pragma unroll
                for (int p = 0; p < 2; ++p) {
                    const float* srcw = W + (size_t)(n0 + p * 64 + srow) * 1024 + k0 + 32 + scol;
                    pw[p][0] = *(const f32x4*)srcw;
                    pw[p][1] = *(const f32x4*)(srcw + 4);
                }
            }
        }
        const unsigned short* ldsA = lds + cur * 8192;
        const unsigned short* ldsB = ldsA + 4096;
        bf16x8 af[4], bfr[4];
#pragma unroll
        for (int i = 0; i < 4; ++i)
            af[i] = *(const bf16x8*)(ldsA + (waveM * 64 + i * 16 + l16) * 32 + quad * 8);
#pragma unroll
        for (int j = 0; j < 4; ++j)
            bfr[j] = *(const bf16x8*)(ldsB + (waveN * 64 + j * 16 + l16) * 32 + quad * 8);
#pragma unroll
        for (int i = 0; i < 4; ++i)
#pragma unroll
            for (int j = 0; j < 4; ++j)
                acc[i][j] = __builtin_amdgcn_mfma_f32_16x16x32_bf16(af[i], bfr[j], acc[i][j], 0, 0, 0);
        if (pf) {
#pragma unroll
            for (int p = 0; p < 2; ++p)
                *(us8*)(lds + nxt * 8192 + (p * 64 + srow) * 32 + scol) = pack8(pa[p][0], pa[p][1]);
            if (!WBF) {
#pragma unroll
                for (int p = 0; p < 2; ++p)
                    *(us8*)(lds + nxt * 8192 + 4096 + (p * 64 + srow) * 32 + scol) = pack8(pw[p][0], pw[p][1]);
            }
        }
        __syncthreads();
        cur = nxt;
    }

#pragma unroll
    for (int j = 0; j < 4; ++j) {
        const int nn = waveN * 64 + j * 16 + l16;
        const float bc = bias[n0 + nn];
#pragma unroll
        for (int i = 0; i < 4; ++i)
#pragma unroll
            for (int r = 0; r < 4; ++r) {
                const int mm = waveM * 64 + i * 16 + quad * 4 + r;
                ldsQ[mm * 136 + nn] = f2bf(acc[i][j][r] + bc);
            }
    }
    __syncthreads();

    f32x4 acc2[4][4] = {};
#pragma unroll
    for (int ks = 0; ks < 64; ks += 32) {
        bf16x8 aq[4], cq[4];
#pragma unroll
        for (int i = 0; i < 4; ++i)
            aq[i] = *(const bf16x8*)&ldsQ[(waveM * 64 + i * 16 + l16) * 136 + waveN * 64 + ks + quad * 8];
#pragma unroll
        for (int j = 0; j < 4; ++j)
            cq[j] = *(const bf16x8*)&ldsC[(waveN * 64 + j * 16 + l16) * 72 + ks + quad * 8];
#pragma unroll
        for (int i = 0; i < 4; ++i)
#pragma unroll
            for (int j = 0; j < 4; ++j)
                acc2[i][j] = __builtin_amdgcn_mfma_f32_16x16x32_bf16(aq[i], cq[j], acc2[i][j], 0, 0, 0);
    }

    const int common = ec[0];
#pragma unroll
    for (int i = 0; i < 4; ++i)
#pragma unroll
        for (int j = 0; j < 4; ++j)
#pragma unroll
            for (int r = 0; r < 4; ++r) {
                const int lrow = m0 + waveM * 64 + i * 16 + quad * 4 + r;
                const int chan = n0 + waveN * 64 + j * 16 + l16;
                float vv = acc2[i][j][r];
                if (!common)
                    vv = bf2f(Vt[((size_t)(lrow >> 12) * 1024 + chan) * 4096 + (lrow & 4095)]) - vv;
                att[(size_t)lrow * 1024 + chan] = f2bf(vv);
            }
}

// ---------------------------------------------------------------------------
// Output GEMM: out[m,n] = sum_k att[m,k]*Wo[n,k] + bo[n]; out fp32.
// A is bf16 (att). WBF: W via gl2lds; else fp32 cvt manual.
// ---------------------------------------------------------------------------
template<bool WBF>
__global__ __launch_bounds__(256)
void gemm_out(const unsigned short* __restrict__ A, const void* __restrict__ Wp,
              const float* __restrict__ bias,
              float* __restrict__ outP)
{
    __shared__ __align__(16) unsigned short lds[16384];

    const int tid = threadIdx.x;
    const int wid = tid >> 6, lane = tid & 63;
    const int quad = lane >> 4, l16 = lane & 15;
    const int waveM = wid >> 1, waveN = wid & 1;
    int m0, n0; swz_tiles(m0, n0);
    const int srow = tid >> 2, scol = (tid & 3) * 8;
    const int r4 = lane >> 2, c8 = (lane & 3) * 8;

    f32x4 acc[4][4] = {};

    // prologue: stage k0=0 into buffer 0
    if (WBF) {
        const unsigned short* W = (const unsigned short*)Wp;
        for (int s = wid; s < 8; s += 4) {
            const int row = s * 16 + r4;
            gl2lds16(A + (size_t)(m0 + row) * 1024 + c8, lds + s * 512);
            gl2lds16(W + (size_t)(n0 + row) * 1024 + c8, lds + 4096 + s * 512);
        }
    } else {
        const float* W = (const float*)Wp;
#pragma unroll
        for (int p = 0; p < 2; ++p) {
            const int row = p * 64 + srow;
            *(us8*)(lds + row * 32 + scol) = *(const us8*)(A + (size_t)(m0 + row) * 1024 + scol);
            *(us8*)(lds + 4096 + row * 32 + scol) = cvt8(W + (size_t)(n0 + row) * 1024 + scol);
        }
    }
    __syncthreads();

    int cur = 0;
    for (int k0 = 0; k0 < 1024; k0 += 32) {
        const int nxt = cur ^ 1;
        if (k0 < 992) {
            if (WBF) {
                const unsigned short* W = (const unsigned short*)Wp;
                for (int s = wid; s < 8; s += 4) {
                    const int row = s * 16 + r4;
                    gl2lds16(A + (size_t)(m0 + row) * 1024 + k0 + 32 + c8,
                             lds + nxt * 8192 + s * 512);
                    gl2lds16(W + (size_t)(n0 + row) * 1024 + k0 + 32 + c8,
                             lds + nxt * 8192 + 4096 + s * 512);
                }
            } else {
                const float* W = (const float*)Wp;
#pragma unroll
                for (int p = 0; p < 2; ++p) {
                    const int row = p * 64 + srow;
                    *(us8*)(lds + nxt * 8192 + row * 32 + scol) =
                        *(const us8*)(A + (size_t)(m0 + row) * 1024 + k0 + 32 + scol);
                    *(us8*)(lds + nxt * 8192 + 4096 + row * 32 + scol) =
                        cvt8(W + (size_t)(n0 + row) * 1024 + k0 + 32 + scol);
                }
            }
        }
        const unsigned short* ldsA = lds + cur * 8192;
        const unsigned short* ldsB = ldsA + 4096;
        bf16x8 af[4], bfr[4];
#pragma unroll
        for (int i = 0; i < 4; ++i)
            af[i] = *(const bf16x8*)(ldsA + (waveM * 64 + i * 16 + l16) * 32 + quad * 8);
#pragma unroll
        for (int j = 0; j < 4; ++j)
            bfr[j] = *(const bf16x8*)(ldsB + (waveN * 64 + j * 16 + l16) * 32 + quad * 8);
#pragma unroll
        for (int i = 0; i < 4; ++i)
#pragma unroll
            for (int j = 0; j < 4; ++j)
                acc[i][j] = __builtin_amdgcn_mfma_f32_16x16x32_bf16(af[i], bfr[j], acc[i][j], 0, 0, 0);
        __syncthreads();
        cur = nxt;
    }

#pragma unroll
    for (int j = 0; j < 4; ++j) {
        const int col = n0 + waveN * 64 + j * 16 + l16;
        const float bc = bias[col];
#pragma unroll
        for (int i = 0; i < 4; ++i)
#pragma unroll
            for (int r = 0; r < 4; ++r) {
                const int row = m0 + waveM * 64 + i * 16 + quad * 4 + r;
                outP[(size_t)row * 1024 + col] = acc[i][j][r] + bc;
            }
    }
}

// ---------------------------------------------------------------------------
extern "C" void kernel_launch(void* const* d_in, const int* in_sizes, int n_in,
                              void* d_out, int out_size, void* d_ws, size_t ws_size,
                              hipStream_t stream)
{
    const float* q  = (const float*)d_in[0];
    const float* k  = (const float*)d_in[1];
    const float* v  = (const float*)d_in[2];
    const float* Wq = (const float*)d_in[3];
    const float* bq = (const float*)d_in[4];
    const float* Wk = (const float*)d_in[5];
    const float* bk = (const float*)d_in[6];
    const float* Wv = (const float*)d_in[7];
    const float* bv = (const float*)d_in[8];
    const float* Wo = (const float*)d_in[9];
    const float* bo = (const float*)d_in[10];
    const int* ec   = (const int*)d_in[11];

    char* ws = (char*)d_ws;
    const size_t NEED_FAST = 76562432; // Et+Vt+W*4+ctxf+S
    const dim3 gblk(8, 128, 1);
    const dim3 gctx(8, 16, 4);

    if (ws_size >= NEED_FAST) {
        unsigned short* Et   = (unsigned short*)(ws);                 // 33.55 MB
        unsigned short* Vt   = (unsigned short*)(ws + 33554432);      // 33.55 MB
        unsigned short* Wkb  = (unsigned short*)(ws + 67108864);      // 2 MB
        unsigned short* Wvb  = (unsigned short*)(ws + 69206016);      // 2 MB
        unsigned short* Wqb  = (unsigned short*)(ws + 71303168);      // 2 MB
        unsigned short* Wob  = (unsigned short*)(ws + 73400320);      // 2 MB
        float*          ctxf = (float*)(ws + 75497472);               // 1 MB
        float*          S    = (float*)(ws + 76546048);               // 16 KB
        unsigned short* att  = Et;                                    // alias (Et dead after ctx)

        hipMemsetAsync(S, 0, 4096 * sizeof(float), stream);
        hipMemsetAsync(ctxf, 0, 4 * 16 * 64 * 64 * sizeof(float), stream);

        cvt_w4<<<dim3(512, 4), 256, 0, stream>>>(Wk, Wv, Wq, Wo, Wkb, Wvb, Wqb, Wob);

        gemm_proj<1, true><<<gblk, 256, 0, stream>>>(k, Wkb, bk, Et, S);
        gemm_proj<2, true><<<gblk, 256, 0, stream>>>(v, Wvb, bv, Vt, nullptr);

        ctx_kernel<<<gctx, 256, 0, stream>>>(Vt, Et, ctxf);

        gemm_qattn<true><<<gblk, 256, 0, stream>>>(q, Wqb, bq, ctxf, S, Vt, ec, att);

        gemm_out<true><<<gblk, 256, 0, stream>>>(att, Wob, bo, (float*)d_out);
    } else {
        // fallback: all-fp32-input path (68.7 MB)
        unsigned short* Et   = (unsigned short*)(ws);
        unsigned short* Vt   = (unsigned short*)(ws + 33554432);
        float*          ctxf = (float*)(ws + 67108864);
        float*          S    = (float*)(ws + 68157440);
        unsigned short* att  = Et;

        hipMemsetAsync(S, 0, 4096 * sizeof(float), stream);
        hipMemsetAsync(ctxf, 0, 4 * 16 * 64 * 64 * sizeof(float), stream);

        gemm_proj<1, false><<<gblk, 256, 0, stream>>>(k, Wk, bk, Et, S);
        gemm_proj<2, false><<<gblk, 256, 0, stream>>>(v, Wv, bv, Vt, nullptr);
        ctx_kernel<<<gctx, 256, 0, stream>>>(Vt, Et, ctxf);
        gemm_qattn<false><<<gblk, 256, 0, stream>>>(q, Wq, bq, ctxf, S, Vt, ec, att);
        gemm_out<false><<<gblk, 256, 0, stream>>>(att, Wo, bo, (float*)d_out);
    }
}

// Round 5
// 449.332 us; speedup vs baseline: 1.1404x; 1.1404x over previous
//
#include <hip/hip_runtime.h>
#include <cmath>

typedef __bf16 bf16x8 __attribute__((ext_vector_type(8)));
typedef float f32x4 __attribute__((ext_vector_type(4)));
typedef unsigned short us8 __attribute__((ext_vector_type(8)));

__device__ __forceinline__ unsigned short f2bf(float f) {
    union { float f; unsigned u; } x; x.f = f;
    unsigned u = x.u + 0x7FFFu + ((x.u >> 16) & 1u);
    return (unsigned short)(u >> 16);
}
__device__ __forceinline__ float bf2f(unsigned short h) {
    union { unsigned u; float f; } x; x.u = ((unsigned)h) << 16;
    return x.f;
}

// pack two f32x4 into bf16x8 (RNE via hw cvt)
__device__ __forceinline__ us8 pack8(f32x4 a, f32x4 b) {
    union { bf16x8 h; us8 u; } cv;
    cv.h[0] = (__bf16)a[0]; cv.h[1] = (__bf16)a[1];
    cv.h[2] = (__bf16)a[2]; cv.h[3] = (__bf16)a[3];
    cv.h[4] = (__bf16)b[0]; cv.h[5] = (__bf16)b[1];
    cv.h[6] = (__bf16)b[2]; cv.h[7] = (__bf16)b[3];
    return cv.u;
}

// load 8 consecutive fp32, convert to bf16x8 (as us8)
__device__ __forceinline__ us8 cvt8(const float* p) {
    f32x4 a = *(const f32x4*)p;
    f32x4 b = *(const f32x4*)(p + 4);
    return pack8(a, b);
}

__device__ __forceinline__ void gl2lds16(const unsigned short* g, unsigned short* l) {
    __builtin_amdgcn_global_load_lds(
        (const __attribute__((address_space(1))) unsigned int*)g,
        (__attribute__((address_space(3))) unsigned int*)l, 16, 0, 0);
}

// fp32 -> bf16 elementwise, 8 elems/thread, exact-size grid
__global__ __launch_bounds__(256)
void cvt_kernel(const float* __restrict__ src, unsigned short* __restrict__ dst) {
    const size_t i = ((size_t)blockIdx.x * 256 + threadIdx.x) * 8;
    *(us8*)(dst + i) = cvt8(src + i);
}

// 4 weight matrices (1M floats each) in one launch; blockIdx.y selects matrix
__global__ __launch_bounds__(256)
void cvt_w4(const float* __restrict__ s0, const float* __restrict__ s1,
            const float* __restrict__ s2, const float* __restrict__ s3,
            unsigned short* __restrict__ d0, unsigned short* __restrict__ d1,
            unsigned short* __restrict__ d2, unsigned short* __restrict__ d3) {
    const float* sp[4] = {s0, s1, s2, s3};
    unsigned short* dp[4] = {d0, d1, d2, d3};
    const float* src = sp[blockIdx.y];
    unsigned short* dst = dp[blockIdx.y];
    const size_t i = ((size_t)blockIdx.x * 256 + threadIdx.x) * 8;
    *(us8*)(dst + i) = cvt8(src + i);
}

// XCD-chunked swizzle: dispatch slot s -> work w so slots with equal s%8
// (same XCD) process contiguous w. nwg=1024, 1024%8==0 -> bijective.
__device__ __forceinline__ void swz_tiles(int& m0, int& n0) {
    const int slot = blockIdx.x + (blockIdx.y << 3);
    const int w = ((slot & 7) << 7) | (slot >> 3);
    m0 = (w >> 3) << 7;
    n0 = (w & 7) << 7;
}

// ---------------------------------------------------------------------------
// Projection GEMM: Y[m,n] = sum_k A[m,k]*W[n,k] + bias[n]; M=16384,N=1024,K=1024
// BF path: 3-buffer gl2lds pipeline with counted vmcnt(4) across raw s_barrier
// (T4): tile t+2's 4 loads stay in flight over the barrier; each tile gets
// ~2 MFMA phases of latency cover. lgkmcnt(0) before the barrier guarantees
// all ds_reads of the to-be-overwritten buffer have returned.
// MODE 1: v = exp(clamp(y)); transposed bf16 outT [B][1024][4096]; col sums->S
// MODE 2: v = y;             transposed bf16 outT
// ---------------------------------------------------------------------------
template<int MODE, bool BF>
__global__ __launch_bounds__(256)
void gemm_proj(const void* __restrict__ Ap, const void* __restrict__ Wp,
               const float* __restrict__ bias,
               unsigned short* __restrict__ outT,
               float* __restrict__ S)
{
    __shared__ __align__(16) unsigned short lds[24576]; // 3x8192 staging | epi 17408

    const int tid = threadIdx.x;
    const int wid = tid >> 6, lane = tid & 63;
    const int quad = lane >> 4, l16 = lane & 15;
    const int waveM = wid >> 1, waveN = wid & 1;
    int m0, n0; swz_tiles(m0, n0);
    const int srow = tid >> 2, scol = (tid & 3) * 8;
    const int r4 = lane >> 2, c8 = (lane & 3) * 8;

    f32x4 acc[4][4] = {};

    if (BF) {
        const unsigned short* A = (const unsigned short*)Ap;
        const unsigned short* W = (const unsigned short*)Wp;
#define STAGE_P(K0, BASE)                                                     \
        for (int s = wid; s < 8; s += 4) {                                    \
            const int row = s * 16 + r4;                                      \
            gl2lds16(A + (size_t)(m0 + row) * 1024 + (K0) + c8, (BASE) + s * 512);          \
            gl2lds16(W + (size_t)(n0 + row) * 1024 + (K0) + c8, (BASE) + 4096 + s * 512);   \
        }
        STAGE_P(0, lds);
        STAGE_P(32, lds + 8192);
        asm volatile("s_waitcnt vmcnt(4) lgkmcnt(0)" ::: "memory"); // tile0 done
        __builtin_amdgcn_s_barrier();

        int cur = 0;
        for (int it = 0; it < 32; ++it) {
            if (it < 30) {
                const int st = (cur >= 1) ? cur - 1 : 2;  // (cur+2)%3
                STAGE_P((it + 2) * 32, lds + st * 8192);
            }
            const unsigned short* ldsA = lds + cur * 8192;
            const unsigned short* ldsB = ldsA + 4096;
            bf16x8 af[4], bfr[4];
#pragma unroll
            for (int i = 0; i < 4; ++i)
                af[i] = *(const bf16x8*)(ldsA + (waveM * 64 + i * 16 + l16) * 32 + quad * 8);
#pragma unroll
            for (int j = 0; j < 4; ++j)
                bfr[j] = *(const bf16x8*)(ldsB + (waveN * 64 + j * 16 + l16) * 32 + quad * 8);
#pragma unroll
            for (int i = 0; i < 4; ++i)
#pragma unroll
                for (int j = 0; j < 4; ++j)
                    acc[i][j] = __builtin_amdgcn_mfma_f32_16x16x32_bf16(af[i], bfr[j], acc[i][j], 0, 0, 0);
            if (it < 30) {
                asm volatile("s_waitcnt vmcnt(4) lgkmcnt(0)" ::: "memory"); // tile it+1 done, it+2 in flight
                __builtin_amdgcn_s_barrier();
            } else if (it == 30) {
                asm volatile("s_waitcnt vmcnt(0) lgkmcnt(0)" ::: "memory");
                __builtin_amdgcn_s_barrier();
            }
            cur = (cur < 2) ? cur + 1 : 0;
        }
#undef STAGE_P
    } else {
        // fallback: 2-buffer, full-sync, inline fp32->bf16 cvt
        const float* A = (const float*)Ap;
        const float* W = (const float*)Wp;
#pragma unroll
        for (int p = 0; p < 2; ++p) {
            *(us8*)(lds + (p * 64 + srow) * 32 + scol) = cvt8(A + (size_t)(m0 + p * 64 + srow) * 1024 + scol);
            *(us8*)(lds + 4096 + (p * 64 + srow) * 32 + scol) = cvt8(W + (size_t)(n0 + p * 64 + srow) * 1024 + scol);
        }
        __syncthreads();
        int cur = 0;
        for (int k0 = 0; k0 < 1024; k0 += 32) {
            const int nxt = cur ^ 1;
            if (k0 < 992) {
#pragma unroll
                for (int p = 0; p < 2; ++p) {
                    *(us8*)(lds + nxt * 8192 + (p * 64 + srow) * 32 + scol) =
                        cvt8(A + (size_t)(m0 + p * 64 + srow) * 1024 + k0 + 32 + scol);
                    *(us8*)(lds + nxt * 8192 + 4096 + (p * 64 + srow) * 32 + scol) =
                        cvt8(W + (size_t)(n0 + p * 64 + srow) * 1024 + k0 + 32 + scol);
                }
            }
            const unsigned short* ldsA = lds + cur * 8192;
            const unsigned short* ldsB = ldsA + 4096;
            bf16x8 af[4], bfr[4];
#pragma unroll
            for (int i = 0; i < 4; ++i)
                af[i] = *(const bf16x8*)(ldsA + (waveM * 64 + i * 16 + l16) * 32 + quad * 8);
#pragma unroll
            for (int j = 0; j < 4; ++j)
                bfr[j] = *(const bf16x8*)(ldsB + (waveN * 64 + j * 16 + l16) * 32 + quad * 8);
#pragma unroll
            for (int i = 0; i < 4; ++i)
#pragma unroll
                for (int j = 0; j < 4; ++j)
                    acc[i][j] = __builtin_amdgcn_mfma_f32_16x16x32_bf16(af[i], bfr[j], acc[i][j], 0, 0, 0);
            __syncthreads();
            cur = nxt;
        }
    }
    __syncthreads();

    const int b = m0 >> 12, l0 = m0 & 4095;
#pragma unroll
    for (int j = 0; j < 4; ++j) {
        const int nn = waveN * 64 + j * 16 + l16;
        const float bc = bias[n0 + nn];
        float ssum = 0.f;
#pragma unroll
        for (int i = 0; i < 4; ++i)
#pragma unroll
            for (int r = 0; r < 4; ++r) {
                const int mm = waveM * 64 + i * 16 + quad * 4 + r;
                float v = acc[i][j][r] + bc;
                if (MODE == 1) v = expf(fminf(fmaxf(v, -30.f), 30.f)); // NaN/inf firewall
                lds[nn * 136 + mm] = f2bf(v);
                ssum += v;
            }
        if (MODE == 1) {
            ssum += __shfl_xor(ssum, 16);
            ssum += __shfl_xor(ssum, 32);
            if (lane < 16)
                atomicAdd(&S[(size_t)b * 1024 + n0 + waveN * 64 + j * 16 + lane], ssum);
        }
    }
    __syncthreads();
    const int seg = (tid & 15) * 8;
#pragma unroll
    for (int it = 0; it < 8; ++it) {
        const int nn = (tid >> 4) + it * 16;
        us8 v = *(const us8*)&lds[nn * 136 + seg];
        *(us8*)(outT + ((size_t)b * 1024 + n0 + nn) * 4096 + l0 + seg) = v;
    }
}

// ---------------------------------------------------------------------------
// Context: ctxf[b][h][e][d] += sum_l Vt[b][h*64+e][l] * Et[b][h*64+d][l]
// reg-prefetch double-buffer; grid (8,16,4) -> 512 blocks, 16 K-iters
// ---------------------------------------------------------------------------
__global__ __launch_bounds__(256)
void ctx_kernel(const unsigned short* __restrict__ Vt,
                const unsigned short* __restrict__ Et,
                float* __restrict__ ctxf)
{
    __shared__ __align__(16) unsigned short lds[8192];

    const int tid = threadIdx.x;
    const int wid = tid >> 6, lane = tid & 63;
    const int quad = lane >> 4, l16 = lane & 15;
    const int b = blockIdx.z, h = blockIdx.y;
    const int lbase = blockIdx.x * 512;

    const unsigned short* Arow = Vt + ((size_t)b * 1024 + h * 64) * 4096; // rows e
    const unsigned short* Brow = Et + ((size_t)b * 1024 + h * 64) * 4096; // rows d

    const int srow = tid >> 2;
    const int scol = (tid & 3) * 8;

    f32x4 acc[4] = {};

    {
        us8 va = *(const us8*)(Arow + (size_t)srow * 4096 + lbase + scol);
        us8 vb = *(const us8*)(Brow + (size_t)srow * 4096 + lbase + scol);
        *(us8*)(lds + srow * 32 + scol) = va;
        *(us8*)(lds + 2048 + srow * 32 + scol) = vb;
    }
    __syncthreads();

    int cur = 0;
    for (int k0 = 0; k0 < 512; k0 += 32) {
        const int nxt = cur ^ 1;
        us8 na = {}, nb = {};
        const bool pf = (k0 < 480);
        if (pf) {
            na = *(const us8*)(Arow + (size_t)srow * 4096 + lbase + k0 + 32 + scol);
            nb = *(const us8*)(Brow + (size_t)srow * 4096 + lbase + k0 + 32 + scol);
        }
        const unsigned short* ldsA = lds + cur * 4096;
        const unsigned short* ldsB = ldsA + 2048;
        bf16x8 a = *(const bf16x8*)(ldsA + (wid * 16 + l16) * 32 + quad * 8);
#pragma unroll
        for (int j = 0; j < 4; ++j) {
            bf16x8 bb = *(const bf16x8*)(ldsB + (j * 16 + l16) * 32 + quad * 8);
            acc[j] = __builtin_amdgcn_mfma_f32_16x16x32_bf16(a, bb, acc[j], 0, 0, 0);
        }
        if (pf) {
            *(us8*)(lds + nxt * 4096 + srow * 32 + scol) = na;
            *(us8*)(lds + nxt * 4096 + 2048 + srow * 32 + scol) = nb;
        }
        __syncthreads();
        cur = nxt;
    }
    float* base = ctxf + ((size_t)(b * 16 + h)) * 4096;
#pragma unroll
    for (int j = 0; j < 4; ++j)
#pragma unroll
        for (int r = 0; r < 4; ++r) {
            const int e = wid * 16 + quad * 4 + r;
            const int d = j * 16 + l16;
            atomicAdd(base + e * 64 + d, acc[j][r]);
        }
}

// ---------------------------------------------------------------------------
// Fused Q-projection + attention (two heads per 128-col tile).
// BF path: 3-buffer counted-vmcnt pipeline (same as gemm_proj).
// LDS: staging [0,24576) during main loop. AFTER the loop: ldsQ [0,17408),
// ldsC [17408,26624) = 128 rows x 72 shorts (9216) -- ctx staged POST-loop
// (fused ctx_norm), since its region aliases staging buffer 2+.
// ---------------------------------------------------------------------------
template<bool BF>
__global__ __launch_bounds__(256)
void gemm_qattn(const void* __restrict__ Ap, const void* __restrict__ Wp,
                const float* __restrict__ bias,
                const float* __restrict__ ctxf,
                const float* __restrict__ Sv,
                const unsigned short* __restrict__ Vt,
                const int* __restrict__ ec,
                unsigned short* __restrict__ att)
{
    __shared__ __align__(16) unsigned short lds[26624];
    unsigned short* ldsQ = lds;              // [128][136] after main loop
    unsigned short* ldsC = lds + 17408;      // [128][72] after main loop

    const int tid = threadIdx.x;
    const int wid = tid >> 6, lane = tid & 63;
    const int quad = lane >> 4, l16 = lane & 15;
    const int waveM = wid >> 1, waveN = wid & 1;
    int m0, n0; swz_tiles(m0, n0);
    const int b = m0 >> 12;
    const int srow = tid >> 2, scol = (tid & 3) * 8;
    const int r4 = lane >> 2, c8 = (lane & 3) * 8;

    f32x4 acc[4][4] = {};

    if (BF) {
        const unsigned short* A = (const unsigned short*)Ap;
        const unsigned short* W = (const unsigned short*)Wp;
#define STAGE_Q(K0, BASE)                                                     \
        for (int s = wid; s < 8; s += 4) {                                    \
            const int row = s * 16 + r4;                                      \
            gl2lds16(A + (size_t)(m0 + row) * 1024 + (K0) + c8, (BASE) + s * 512);          \
            gl2lds16(W + (size_t)(n0 + row) * 1024 + (K0) + c8, (BASE) + 4096 + s * 512);   \
        }
        STAGE_Q(0, lds);
        STAGE_Q(32, lds + 8192);
        asm volatile("s_waitcnt vmcnt(4) lgkmcnt(0)" ::: "memory");
        __builtin_amdgcn_s_barrier();

        int cur = 0;
        for (int it = 0; it < 32; ++it) {
            if (it < 30) {
                const int st = (cur >= 1) ? cur - 1 : 2;  // (cur+2)%3
                STAGE_Q((it + 2) * 32, lds + st * 8192);
            }
            const unsigned short* ldsA = lds + cur * 8192;
            const unsigned short* ldsB = ldsA + 4096;
            bf16x8 af[4], bfr[4];
#pragma unroll
            for (int i = 0; i < 4; ++i)
                af[i] = *(const bf16x8*)(ldsA + (waveM * 64 + i * 16 + l16) * 32 + quad * 8);
#pragma unroll
            for (int j = 0; j < 4; ++j)
                bfr[j] = *(const bf16x8*)(ldsB + (waveN * 64 + j * 16 + l16) * 32 + quad * 8);
#pragma unroll
            for (int i = 0; i < 4; ++i)
#pragma unroll
                for (int j = 0; j < 4; ++j)
                    acc[i][j] = __builtin_amdgcn_mfma_f32_16x16x32_bf16(af[i], bfr[j], acc[i][j], 0, 0, 0);
            if (it < 30) {
                asm volatile("s_waitcnt vmcnt(4) lgkmcnt(0)" ::: "memory");
                __builtin_amdgcn_s_barrier();
            } else if (it == 30) {
                asm volatile("s_waitcnt vmcnt(0) lgkmcnt(0)" ::: "memory");
                __builtin_amdgcn_s_barrier();
            }
            cur = (cur < 2) ? cur + 1 : 0;
        }
#undef STAGE_Q
    } else {
        const float* A = (const float*)Ap;
        const float* W = (const float*)Wp;
#pragma unroll
        for (int p = 0; p < 2; ++p) {
            *(us8*)(lds + (p * 64 + srow) * 32 + scol) = cvt8(A + (size_t)(m0 + p * 64 + srow) * 1024 + scol);
            *(us8*)(lds + 4096 + (p * 64 + srow) * 32 + scol) = cvt8(W + (size_t)(n0 + p * 64 + srow) * 1024 + scol);
        }
        __syncthreads();
        int cur = 0;
        for (int k0 = 0; k0 < 1024; k0 += 32) {
            const int nxt = cur ^ 1;
            if (k0 < 992) {
#pragma unroll
                for (int p = 0; p < 2; ++p) {
                    *(us8*)(lds + nxt * 8192 + (p * 64 + srow) * 32 + scol) =
                        cvt8(A + (size_t)(m0 + p * 64 + srow) * 1024 + k0 + 32 + scol);
                    *(us8*)(lds + nxt * 8192 + 4096 + (p * 64 + srow) * 32 + scol) =
                        cvt8(W + (size_t)(n0 + p * 64 + srow) * 1024 + k0 + 32 + scol);
                }
            }
            const unsigned short* ldsA = lds + cur * 8192;
            const unsigned short* ldsB = ldsA + 4096;
            bf16x8 af[4], bfr[4];
#pragma unroll
            for (int i = 0; i < 4; ++i)
                af[i] = *(const bf16x8*)(ldsA + (waveM * 64 + i * 16 + l16) * 32 + quad * 8);
#pragma unroll
            for (int j = 0; j < 4; ++j)
                bfr[j] = *(const bf16x8*)(ldsB + (waveN * 64 + j * 16 + l16) * 32 + quad * 8);
#pragma unroll
            for (int i = 0; i < 4; ++i)
#pragma unroll
                for (int j = 0; j < 4; ++j)
                    acc[i][j] = __builtin_amdgcn_mfma_f32_16x16x32_bf16(af[i], bfr[j], acc[i][j], 0, 0, 0);
            __syncthreads();
            cur = nxt;
        }
    }
    __syncthreads();

    { // stage normalized ctx for both heads of this tile (fused ctx_norm).
      // Issued first so the global-load latency hides under the ldsQ writes.
        const int e2 = tid >> 1;
        const int sg = (tid & 1) * 32;
        const int hh = (n0 >> 6) + (e2 >> 6);
        const float* srcf = ctxf + (((size_t)(b * 16) + hh) * 64 + (e2 & 63)) * 64 + sg;
        const float* Sp = Sv + (size_t)b * 1024 + hh * 64 + sg;
#pragma unroll
        for (int u = 0; u < 4; ++u) {
            f32x4 c0 = *(const f32x4*)(srcf + u * 8);
            f32x4 c1 = *(const f32x4*)(srcf + u * 8 + 4);
            union { bf16x8 h; us8 uu; } cv;
#pragma unroll
            for (int j = 0; j < 4; ++j) cv.h[j] = (__bf16)(c0[j] / Sp[u * 8 + j]);
#pragma unroll
            for (int j = 0; j < 4; ++j) cv.h[4 + j] = (__bf16)(c1[j] / Sp[u * 8 + 4 + j]);
            *(us8*)&ldsC[(size_t)e2 * 72 + sg + u * 8] = cv.uu;
        }
    }

#pragma unroll
    for (int j = 0; j < 4; ++j) {
        const int nn = waveN * 64 + j * 16 + l16;
        const float bc = bias[n0 + nn];
#pragma unroll
        for (int i = 0; i < 4; ++i)
#pragma unroll
            for (int r = 0; r < 4; ++r) {
                const int mm = waveM * 64 + i * 16 + quad * 4 + r;
                ldsQ[mm * 136 + nn] = f2bf(acc[i][j][r] + bc);
            }
    }
    __syncthreads();

    f32x4 acc2[4][4] = {};
#pragma unroll
    for (int ks = 0; ks < 64; ks += 32) {
        bf16x8 aq[4], cq[4];
#pragma unroll
        for (int i = 0; i < 4; ++i)
            aq[i] = *(const bf16x8*)&ldsQ[(waveM * 64 + i * 16 + l16) * 136 + waveN * 64 + ks + quad * 8];
#pragma unroll
        for (int j = 0; j < 4; ++j)
            cq[j] = *(const bf16x8*)&ldsC[(waveN * 64 + j * 16 + l16) * 72 + ks + quad * 8];
#pragma unroll
        for (int i = 0; i < 4; ++i)
#pragma unroll
            for (int j = 0; j < 4; ++j)
                acc2[i][j] = __builtin_amdgcn_mfma_f32_16x16x32_bf16(aq[i], cq[j], acc2[i][j], 0, 0, 0);
    }

    const int common = ec[0];
#pragma unroll
    for (int i = 0; i < 4; ++i)
#pragma unroll
        for (int j = 0; j < 4; ++j)
#pragma unroll
            for (int r = 0; r < 4; ++r) {
                const int lrow = m0 + waveM * 64 + i * 16 + quad * 4 + r;
                const int chan = n0 + waveN * 64 + j * 16 + l16;
                float vv = acc2[i][j][r];
                if (!common)
                    vv = bf2f(Vt[((size_t)(lrow >> 12) * 1024 + chan) * 4096 + (lrow & 4095)]) - vv;
                att[(size_t)lrow * 1024 + chan] = f2bf(vv);
            }
}

// ---------------------------------------------------------------------------
// Output GEMM: out[m,n] = sum_k att[m,k]*Wo[n,k] + bo[n]; out fp32.
// BF path: 3-buffer counted-vmcnt pipeline.
// ---------------------------------------------------------------------------
template<bool BF>
__global__ __launch_bounds__(256)
void gemm_out(const unsigned short* __restrict__ A, const void* __restrict__ Wp,
              const float* __restrict__ bias,
              float* __restrict__ outP)
{
    __shared__ __align__(16) unsigned short lds[24576];

    const int tid = threadIdx.x;
    const int wid = tid >> 6, lane = tid & 63;
    const int quad = lane >> 4, l16 = lane & 15;
    const int waveM = wid >> 1, waveN = wid & 1;
    int m0, n0; swz_tiles(m0, n0);
    const int srow = tid >> 2, scol = (tid & 3) * 8;
    const int r4 = lane >> 2, c8 = (lane & 3) * 8;

    f32x4 acc[4][4] = {};

    if (BF) {
        const unsigned short* W = (const unsigned short*)Wp;
#define STAGE_O(K0, BASE)                                                     \
        for (int s = wid; s < 8; s += 4) {                                    \
            const int row = s * 16 + r4;                                      \
            gl2lds16(A + (size_t)(m0 + row) * 1024 + (K0) + c8, (BASE) + s * 512);          \
            gl2lds16(W + (size_t)(n0 + row) * 1024 + (K0) + c8, (BASE) + 4096 + s * 512);   \
        }
        STAGE_O(0, lds);
        STAGE_O(32, lds + 8192);
        asm volatile("s_waitcnt vmcnt(4) lgkmcnt(0)" ::: "memory");
        __builtin_amdgcn_s_barrier();

        int cur = 0;
        for (int it = 0; it < 32; ++it) {
            if (it < 30) {
                const int st = (cur >= 1) ? cur - 1 : 2;  // (cur+2)%3
                STAGE_O((it + 2) * 32, lds + st * 8192);
            }
            const unsigned short* ldsA = lds + cur * 8192;
            const unsigned short* ldsB = ldsA + 4096;
            bf16x8 af[4], bfr[4];
#pragma unroll
            for (int i = 0; i < 4; ++i)
                af[i] = *(const bf16x8*)(ldsA + (waveM * 64 + i * 16 + l16) * 32 + quad * 8);
#pragma unroll
            for (int j = 0; j < 4; ++j)
                bfr[j] = *(const bf16x8*)(ldsB + (waveN * 64 + j * 16 + l16) * 32 + quad * 8);
#pragma unroll
            for (int i = 0; i < 4; ++i)
#pragma unroll
                for (int j = 0; j < 4; ++j)
                    acc[i][j] = __builtin_amdgcn_mfma_f32_16x16x32_bf16(af[i], bfr[j], acc[i][j], 0, 0, 0);
            if (it < 30) {
                asm volatile("s_waitcnt vmcnt(4) lgkmcnt(0)" ::: "memory");
                __builtin_amdgcn_s_barrier();
            } else if (it == 30) {
                asm volatile("s_waitcnt vmcnt(0) lgkmcnt(0)" ::: "memory");
                __builtin_amdgcn_s_barrier();
            }
            cur = (cur < 2) ? cur + 1 : 0;
        }
#undef STAGE_O
    } else {
        const float* W = (const float*)Wp;
#pragma unroll
        for (int p = 0; p < 2; ++p) {
            *(us8*)(lds + (p * 64 + srow) * 32 + scol) = *(const us8*)(A + (size_t)(m0 + p * 64 + srow) * 1024 + scol);
            *(us8*)(lds + 4096 + (p * 64 + srow) * 32 + scol) = cvt8(W + (size_t)(n0 + p * 64 + srow) * 1024 + scol);
        }
        __syncthreads();
        int cur = 0;
        for (int k0 = 0; k0 < 1024; k0 += 32) {
            const int nxt = cur ^ 1;
            if (k0 < 992) {
#pragma unroll
                for (int p = 0; p < 2; ++p) {
                    *(us8*)(lds + nxt * 8192 + (p * 64 + srow) * 32 + scol) =
                        *(const us8*)(A + (size_t)(m0 + p * 64 + srow) * 1024 + k0 + 32 + scol);
                    *(us8*)(lds + nxt * 8192 + 4096 + (p * 64 + srow) * 32 + scol) =
                        cvt8(W + (size_t)(n0 + p * 64 + srow) * 1024 + k0 + 32 + scol);
                }
            }
            const unsigned short* ldsA = lds + cur * 8192;
            const unsigned short* ldsB = ldsA + 4096;
            bf16x8 af[4], bfr[4];
#pragma unroll
            for (int i = 0; i < 4; ++i)
                af[i] = *(const bf16x8*)(ldsA + (waveM * 64 + i * 16 + l16) * 32 + quad * 8);
#pragma unroll
            for (int j = 0; j < 4; ++j)
                bfr[j] = *(const bf16x8*)(ldsB + (waveN * 64 + j * 16 + l16) * 32 + quad * 8);
#pragma unroll
            for (int i = 0; i < 4; ++i)
#pragma unroll
                for (int j = 0; j < 4; ++j)
                    acc[i][j] = __builtin_amdgcn_mfma_f32_16x16x32_bf16(af[i], bfr[j], acc[i][j], 0, 0, 0);
            __syncthreads();
            cur = nxt;
        }
    }

#pragma unroll
    for (int j = 0; j < 4; ++j) {
        const int col = n0 + waveN * 64 + j * 16 + l16;
        const float bc = bias[col];
#pragma unroll
        for (int i = 0; i < 4; ++i)
#pragma unroll
            for (int r = 0; r < 4; ++r) {
                const int row = m0 + waveM * 64 + i * 16 + quad * 4 + r;
                outP[(size_t)row * 1024 + col] = acc[i][j][r] + bc;
            }
    }
}

// ---------------------------------------------------------------------------
extern "C" void kernel_launch(void* const* d_in, const int* in_sizes, int n_in,
                              void* d_out, int out_size, void* d_ws, size_t ws_size,
                              hipStream_t stream)
{
    const float* q  = (const float*)d_in[0];
    const float* k  = (const float*)d_in[1];
    const float* v  = (const float*)d_in[2];
    const float* Wq = (const float*)d_in[3];
    const float* bq = (const float*)d_in[4];
    const float* Wk = (const float*)d_in[5];
    const float* bk = (const float*)d_in[6];
    const float* Wv = (const float*)d_in[7];
    const float* bv = (const float*)d_in[8];
    const float* Wo = (const float*)d_in[9];
    const float* bo = (const float*)d_in[10];
    const int* ec   = (const int*)d_in[11];

    char* ws = (char*)d_ws;
    const size_t NEED_FAST = 110641152; // Ab+Et+Vt+W*4+ctxf+S
    const dim3 gblk(8, 128, 1);
    const dim3 gctx(8, 16, 4);

    if (ws_size >= NEED_FAST) {
        unsigned short* Ab   = (unsigned short*)(ws);                 // 33.55 MB (reused k,v,q)
        unsigned short* Et   = (unsigned short*)(ws + 33554432);      // 33.55 MB
        unsigned short* Vt   = (unsigned short*)(ws + 67108864);      // 33.55 MB
        unsigned short* Wkb  = (unsigned short*)(ws + 100663296);     // 2 MB
        unsigned short* Wvb  = (unsigned short*)(ws + 102760448);     // 2 MB
        unsigned short* Wqb  = (unsigned short*)(ws + 104857600);     // 2 MB
        unsigned short* Wob  = (unsigned short*)(ws + 106954752);     // 2 MB
        float*          ctxf = (float*)(ws + 109051904);              // 1 MB
        float*          S    = (float*)(ws + 110100480);              // 16 KB
        unsigned short* att  = Et;                                    // alias (Et dead after ctx)

        hipMemsetAsync(S, 0, 4096 * sizeof(float), stream);
        hipMemsetAsync(ctxf, 0, 4 * 16 * 64 * 64 * sizeof(float), stream);

        cvt_w4<<<dim3(512, 4), 256, 0, stream>>>(Wk, Wv, Wq, Wo, Wkb, Wvb, Wqb, Wob);

        cvt_kernel<<<8192, 256, 0, stream>>>(k, Ab);
        gemm_proj<1, true><<<gblk, 256, 0, stream>>>(Ab, Wkb, bk, Et, S);

        cvt_kernel<<<8192, 256, 0, stream>>>(v, Ab);
        gemm_proj<2, true><<<gblk, 256, 0, stream>>>(Ab, Wvb, bv, Vt, nullptr);

        ctx_kernel<<<gctx, 256, 0, stream>>>(Vt, Et, ctxf);

        cvt_kernel<<<8192, 256, 0, stream>>>(q, Ab);
        gemm_qattn<true><<<gblk, 256, 0, stream>>>(Ab, Wqb, bq, ctxf, S, Vt, ec, att);

        gemm_out<true><<<gblk, 256, 0, stream>>>(att, Wob, bo, (float*)d_out);
    } else {
        // fallback: all-fp32-input path (68.7 MB)
        unsigned short* Et   = (unsigned short*)(ws);
        unsigned short* Vt   = (unsigned short*)(ws + 33554432);
        float*          ctxf = (float*)(ws + 67108864);
        float*          S    = (float*)(ws + 68157440);
        unsigned short* att  = Et;

        hipMemsetAsync(S, 0, 4096 * sizeof(float), stream);
        hipMemsetAsync(ctxf, 0, 4 * 16 * 64 * 64 * sizeof(float), stream);

        gemm_proj<1, false><<<gblk, 256, 0, stream>>>(k, Wk, bk, Et, S);
        gemm_proj<2, false><<<gblk, 256, 0, stream>>>(v, Wv, bv, Vt, nullptr);
        ctx_kernel<<<gctx, 256, 0, stream>>>(Vt, Et, ctxf);
        gemm_qattn<false><<<gblk, 256, 0, stream>>>(q, Wq, bq, ctxf, S, Vt, ec, att);
        gemm_out<false><<<gblk, 256, 0, stream>>>(att, Wo, bo, (float*)d_out);
    }
}